// Round 2
// baseline (56.146 us; speedup 1.0000x reference)
//
#include <hip/hip_runtime.h>
#include <hip/hip_bf16.h>

// Problem: B=16384, I=512, H=512.
// Output = modrelu(complex(inputs@w_ih.T [:, :512], [:, 512:]), b_h)
// The FFT/reflect/perm state path in the reference is DEAD CODE (preact unused).

typedef __attribute__((ext_vector_type(8))) short bf16x8;
typedef __attribute__((ext_vector_type(4))) float f32x4;

#define BM 128
#define BK 64
#define KDIM 512
#define NDIM 1024
#define NKT (KDIM / BK)   // 8 K-tiles

__device__ __forceinline__ unsigned short f2bf(float f) {
    unsigned u = __builtin_bit_cast(unsigned, f);
    u += 0x7fffu + ((u >> 16) & 1u);   // round-to-nearest-even
    return (unsigned short)(u >> 16);
}

__global__ void cvt_f32_bf16(const float* __restrict__ src,
                             unsigned short* __restrict__ dst, int n4) {
    int i = blockIdx.x * blockDim.x + threadIdx.x;
    int stride = gridDim.x * blockDim.x;
    for (; i < n4; i += stride) {
        float4 v = reinterpret_cast<const float4*>(src)[i];
        ushort4 o;
        o.x = f2bf(v.x); o.y = f2bf(v.y); o.z = f2bf(v.z); o.w = f2bf(v.w);
        reinterpret_cast<ushort4*>(dst)[i] = o;
    }
}

__device__ __forceinline__ void gload_lds16(const void* g, void* l) {
    __builtin_amdgcn_global_load_lds(
        (const __attribute__((address_space(1))) unsigned int*)g,
        (__attribute__((address_space(3))) unsigned int*)l, 16, 0, 0);
}

// Block: 128 M-rows x (64 re-cols + 64 im-cols paired). 4 waves in 2Mx2N grid,
// each wave computes 64 rows x 32 col-pairs (4x4 16x16 fragments: jn 0..1 = re,
// jn 2..3 = im). 2-phase pipeline: stage tile t+1 before computing tile t;
// counted via single vmcnt(0)+barrier AFTER compute (T3-minimum recipe).
__global__ __launch_bounds__(256) void gemm_modrelu(
    const unsigned short* __restrict__ A,   // 16384 x 512 bf16
    const unsigned short* __restrict__ W,   // 1024 x 512 bf16
    const float* __restrict__ bh,           // 512
    float* __restrict__ out)                // 16384 x 1024 f32
{
    __shared__ unsigned short At[2][BM * BK];  // 2 x 16 KiB
    __shared__ unsigned short Bt[2][BM * BK];  // 2 x 16 KiB  (total 64 KiB)

    const int tid = threadIdx.x;
    const int w   = tid >> 6;
    const int l   = tid & 63;

    // T1: XCD-chunked bijective swizzle. 1024 blocks, 8 XCDs, 128 logical/XCD.
    // All 8 nb-blocks sharing an A-panel land on the same XCD's L2.
    const int bx = blockIdx.x;
    const int lg = (bx & 7) * 128 + (bx >> 3);
    const int mb = lg >> 3;        // 128 m-blocks of 128 rows
    const int nb = lg & 7;         // 8 n-blocks of 64 col-pairs

    const int l15 = l & 15;
    const int l4  = l >> 4;
    const int wm  = w >> 1;        // 0,1 : M half (64 rows)
    const int wn  = w & 1;         // 0,1 : N half (32 col-pairs)

    // staging: each issue stages 32 rows (8 per wave); lane l writes physical
    // 16B slot (l&7) of row (l>>3); global source segment pre-swizzled (T2).
    const int srow = w * 8 + (l >> 3);
    const int sseg = (l & 7) ^ ((l >> 3) & 7);
    const size_t a_rowbase = (size_t)mb * BM;

    f32x4 acc[4][4];
#pragma unroll
    for (int i = 0; i < 4; ++i)
#pragma unroll
        for (int j = 0; j < 4; ++j) acc[i][j] = f32x4{0.f, 0.f, 0.f, 0.f};

    auto stage = [&](int kt, int buf) {
        const int k0 = kt * BK;
#pragma unroll
        for (int is = 0; is < 4; ++is) {
            int row = is * 32 + srow;
            const unsigned short* g = A + (a_rowbase + row) * KDIM + k0 + sseg * 8;
            gload_lds16(g, &At[buf][(is * 32 + w * 8) * BK]);  // wave-uniform base
        }
#pragma unroll
        for (int is = 0; is < 4; ++is) {
            int brow = is * 32 + srow;
            // B-tile rows 0..63 = W[nb*64 + r] (re), rows 64..127 = W[512 + nb*64 + r] (im)
            int wrow = nb * 64 + (brow & 63) + ((brow >> 6) << 9);
            const unsigned short* g = W + (size_t)wrow * KDIM + k0 + sseg * 8;
            gload_lds16(g, &Bt[buf][(is * 32 + w * 8) * BK]);
        }
    };

    // prologue
    stage(0, 0);
    asm volatile("s_waitcnt vmcnt(0)" ::: "memory");
    __builtin_amdgcn_s_barrier();

#pragma unroll
    for (int kt = 0; kt < NKT; ++kt) {
        const int cur = kt & 1;
        if (kt + 1 < NKT) stage(kt + 1, cur ^ 1);   // issue next-tile loads FIRST

#pragma unroll
        for (int ks = 0; ks < 2; ++ks) {
            bf16x8 af[4], bfr[4];
#pragma unroll
            for (int i = 0; i < 4; ++i) {
                int row  = wm * 64 + i * 16 + l15;
                int slot = (ks * 4 + l4) ^ (row & 7);
                af[i] = *(const bf16x8*)(&At[cur][row * BK + slot * 8]);
            }
#pragma unroll
            for (int jn = 0; jn < 4; ++jn) {
                int row  = (jn < 2) ? (wn * 32 + jn * 16 + l15)
                                    : (64 + wn * 32 + (jn - 2) * 16 + l15);
                int slot = (ks * 4 + l4) ^ (row & 7);
                bfr[jn] = *(const bf16x8*)(&Bt[cur][row * BK + slot * 8]);
            }
#pragma unroll
            for (int i = 0; i < 4; ++i)
#pragma unroll
                for (int jn = 0; jn < 4; ++jn)
                    acc[i][jn] = __builtin_amdgcn_mfma_f32_16x16x32_bf16(
                        af[i], bfr[jn], acc[i][jn], 0, 0, 0);
        }
        // next tile's loads overlapped with the compute above; drain + sync once
        asm volatile("s_waitcnt vmcnt(0) lgkmcnt(0)" ::: "memory");
        __builtin_amdgcn_s_barrier();
    }

    // ---- fused modReLU epilogue ----
    // C/D layout (m89): col = lane&15 (n), row = (lane>>4)*4 + j (m)
#pragma unroll
    for (int jn = 0; jn < 2; ++jn) {
        int n = nb * 64 + wn * 32 + jn * 16 + l15;
        float b = bh[n];
#pragma unroll
        for (int i = 0; i < 4; ++i) {
#pragma unroll
            for (int j = 0; j < 4; ++j) {
                int m = mb * BM + wm * 64 + i * 16 + l4 * 4 + j;
                float re  = acc[i][jn][j];
                float imv = acc[i][jn + 2][j];
                float norm  = sqrtf(re * re + imv * imv);
                float scale = fmaxf(norm + b, 0.f) * __builtin_amdgcn_rcpf(norm + 1e-6f);
                float* po = out + (size_t)m * NDIM + n;
                __builtin_nontemporal_store(re  * scale, po);        // don't pollute L2
                __builtin_nontemporal_store(imv * scale, po + 512);
            }
        }
    }
}

extern "C" void kernel_launch(void* const* d_in, const int* in_sizes, int n_in,
                              void* d_out, int out_size, void* d_ws, size_t ws_size,
                              hipStream_t stream) {
    const float* inputs = (const float*)d_in[0];   // (16384, 512)
    const float* w_ih   = (const float*)d_in[2];   // (1024, 512)
    const float* b_h    = (const float*)d_in[3];   // (512,)
    float* out = (float*)d_out;                    // (16384, 1024)

    unsigned short* Abf = (unsigned short*)d_ws;                          // 16 MiB
    unsigned short* Wbf = (unsigned short*)((char*)d_ws + (size_t)16384 * 512 * 2);

    // convert inputs and weights to bf16
    cvt_f32_bf16<<<2048, 256, 0, stream>>>(inputs, Abf, (16384 * 512) / 4);
    cvt_f32_bf16<<<512,  256, 0, stream>>>(w_ih,   Wbf, (1024 * 512) / 4);

    // fused GEMM + modReLU: grid = (16384/128) m-blocks * 8 n-blocks
    gemm_modrelu<<<128 * 8, 256, 0, stream>>>(Abf, Wbf, b_h, out);
}

// Round 3
// 44.588 us; speedup vs baseline: 1.2592x; 1.2592x over previous
//
#include <hip/hip_runtime.h>
#include <hip/hip_bf16.h>

// Problem: B=16384, I=512, H=512.
// Output = modrelu(complex(inputs@w_ih.T [:, :512], [:, 512:]), b_h)
// The FFT/reflect/perm state path in the reference is DEAD CODE (preact unused).

typedef __attribute__((ext_vector_type(8))) short bf16x8;
typedef __attribute__((ext_vector_type(4))) float f32x4;

#define BM 256            // M rows per block
#define BK 64             // K per tile
#define KDIM 512
#define NDIM 1024
#define NKT (KDIM / BK)   // 8 K-tiles

__device__ __forceinline__ unsigned short f2bf(float f) {
    unsigned u = __builtin_bit_cast(unsigned, f);
    u += 0x7fffu + ((u >> 16) & 1u);   // round-to-nearest-even
    return (unsigned short)(u >> 16);
}

// single conversion dispatch for both A and W
__global__ __launch_bounds__(256) void cvt_both(
    const float* __restrict__ A, const float* __restrict__ W,
    unsigned short* __restrict__ Abf, unsigned short* __restrict__ Wbf,
    int nA4, int nTot4) {
    int i = blockIdx.x * blockDim.x + threadIdx.x;
    int stride = gridDim.x * blockDim.x;
    for (; i < nTot4; i += stride) {
        float4 v;
        if (i < nA4) v = reinterpret_cast<const float4*>(A)[i];
        else         v = reinterpret_cast<const float4*>(W)[i - nA4];
        ushort4 o;
        o.x = f2bf(v.x); o.y = f2bf(v.y); o.z = f2bf(v.z); o.w = f2bf(v.w);
        if (i < nA4) reinterpret_cast<ushort4*>(Abf)[i] = o;
        else         reinterpret_cast<ushort4*>(Wbf)[i - nA4] = o;
    }
}

__device__ __forceinline__ void gload_lds16(const void* g, void* l) {
    __builtin_amdgcn_global_load_lds(
        (const __attribute__((address_space(1))) unsigned int*)g,
        (__attribute__((address_space(3))) unsigned int*)l, 16, 0, 0);
}

// 256x256 tile (256 M-rows x 128 re/im col-pairs), 8 waves in 2M x 4N grid.
// Per wave: 128 rows x 64 cols = acc[8][4] (jn 0..1 re, jn 2..3 im of same pairs).
// B-tile rows 0..127 = W[cb*128+r] (re), 128..255 = W[512+cb*128+r] (im).
// Pipeline: dbuf LDS, prefetch 1 K-tile ahead, counted vmcnt(8) steady state.
__global__ __launch_bounds__(512, 2) void gemm_modrelu(
    const unsigned short* __restrict__ A,   // 16384 x 512 bf16
    const unsigned short* __restrict__ W,   // 1024 x 512 bf16
    const float* __restrict__ bh,           // 512
    float* __restrict__ out)                // 16384 x 1024 f32
{
    __shared__ unsigned short At[2][BM * BK];  // 2 x 32 KiB
    __shared__ unsigned short Bt[2][BM * BK];  // 2 x 32 KiB (128 KiB total)

    const int tid = threadIdx.x;
    const int w   = tid >> 6;
    const int l   = tid & 63;
    const int l15 = l & 15;
    const int l4  = l >> 4;
    const int wm  = w >> 2;        // 0..1 : M half (128 rows)
    const int wn  = w & 3;         // 0..3 : 32 col-pairs

    // T1: XCD-chunked swizzle (256 blocks, 8 XCDs, 32/XCD). Each XCD works on
    // 8 consecutive mb panels x all 4 cb: working set ~3 MB fits its 4 MB L2.
    const int bx = blockIdx.x;
    const int lg = (bx & 7) * 32 + (bx >> 3);
    const int mb = lg >> 2;        // 64 m-blocks of 256 rows
    const int cb = lg & 3;         // 4 col-blocks of 128 pairs

    // staging: wave w stages rows [w*32, w*32+32) of A-tile and B-tile,
    // 4 issues of 8 rows each; lane l -> row (l>>3), physical 16B slot (l&7).
    // Global segment pre-swizzled (T2 both-sides): seg = (l&7) ^ (l>>3).
    const int srow = l >> 3;
    const int sseg = (l & 7) ^ srow;

    const unsigned short* ga[4];
    const unsigned short* gb[4];
    int ldso[4];
#pragma unroll
    for (int is = 0; is < 4; ++is) {
        int row  = w * 32 + is * 8 + srow;
        ga[is]   = A + (size_t)(mb * BM + row) * KDIM + sseg * 8;
        int wrow = (row >> 7) * 512 + cb * 128 + (row & 127);  // re rows then im rows
        gb[is]   = W + (size_t)wrow * KDIM + sseg * 8;
        ldso[is] = (w * 32 + is * 8) * BK;                     // wave-uniform LDS base
    }

    f32x4 acc[8][4];
#pragma unroll
    for (int i = 0; i < 8; ++i)
#pragma unroll
        for (int j = 0; j < 4; ++j) acc[i][j] = f32x4{0.f, 0.f, 0.f, 0.f};

    auto stage = [&](int kt, int buf) {
#pragma unroll
        for (int is = 0; is < 4; ++is)
            gload_lds16(ga[is] + kt * BK, &At[buf][ldso[is]]);
#pragma unroll
        for (int is = 0; is < 4; ++is)
            gload_lds16(gb[is] + kt * BK, &Bt[buf][ldso[is]]);
    };

    // prologue: tiles 0 and 1 in flight (8 vmem ops each)
    stage(0, 0);
    stage(1, 1);
    asm volatile("s_waitcnt vmcnt(8)" ::: "memory");   // tile 0 resident
    __builtin_amdgcn_s_barrier();

#pragma unroll
    for (int kt = 0; kt < NKT; ++kt) {
        const int buf = kt & 1;

#pragma unroll
        for (int ks = 0; ks < 2; ++ks) {
            bf16x8 af[8], bf[4];
            const int slot = (ks * 4 + l4) ^ (l15 & 7);
#pragma unroll
            for (int i = 0; i < 8; ++i) {
                int row = wm * 128 + i * 16 + l15;
                af[i] = *(const bf16x8*)(&At[buf][row * BK + slot * 8]);
            }
#pragma unroll
            for (int jn = 0; jn < 4; ++jn) {
                int row = (jn < 2) ? (wn * 32 + jn * 16 + l15)
                                   : (128 + wn * 32 + (jn - 2) * 16 + l15);
                bf[jn] = *(const bf16x8*)(&Bt[buf][row * BK + slot * 8]);
            }
            asm volatile("s_waitcnt lgkmcnt(0)" ::: "memory");
            __builtin_amdgcn_sched_barrier(0);
            __builtin_amdgcn_s_setprio(1);
#pragma unroll
            for (int i = 0; i < 8; ++i)
#pragma unroll
                for (int jn = 0; jn < 4; ++jn)
                    acc[i][jn] = __builtin_amdgcn_mfma_f32_16x16x32_bf16(
                        af[i], bf[jn], acc[i][jn], 0, 0, 0);
            __builtin_amdgcn_s_setprio(0);
        }

        __builtin_amdgcn_s_barrier();          // all waves done reading buf
        if (kt + 2 < NKT) stage(kt + 2, buf);  // overwrite buf with tile kt+2
        if (kt < NKT - 1) {
            // wait for tile kt+1 (oldest 8 in flight); keep kt+2's 8 in flight
            if (kt + 2 < NKT) asm volatile("s_waitcnt vmcnt(8)" ::: "memory");
            else              asm volatile("s_waitcnt vmcnt(0)" ::: "memory");
            __builtin_amdgcn_s_barrier();      // tile kt+1 visible to all waves
        }
    }

    // ---- fused modReLU epilogue ----
    // C/D layout (m89): col = lane&15 (n), row = (lane>>4)*4 + j (m)
#pragma unroll
    for (int jn = 0; jn < 2; ++jn) {
        int n = cb * 128 + wn * 32 + jn * 16 + l15;
        float b = bh[n];
#pragma unroll
        for (int i = 0; i < 8; ++i) {
#pragma unroll
            for (int j = 0; j < 4; ++j) {
                int m = mb * BM + wm * 128 + i * 16 + l4 * 4 + j;
                float re  = acc[i][jn][j];
                float imv = acc[i][jn + 2][j];
                float norm  = sqrtf(re * re + imv * imv);
                float scale = fmaxf(norm + b, 0.f) * __builtin_amdgcn_rcpf(norm + 1e-6f);
                float* po = out + (size_t)m * NDIM + n;
                __builtin_nontemporal_store(re  * scale, po);
                __builtin_nontemporal_store(imv * scale, po + 512);
            }
        }
    }
}

extern "C" void kernel_launch(void* const* d_in, const int* in_sizes, int n_in,
                              void* d_out, int out_size, void* d_ws, size_t ws_size,
                              hipStream_t stream) {
    const float* inputs = (const float*)d_in[0];   // (16384, 512)
    const float* w_ih   = (const float*)d_in[2];   // (1024, 512)
    const float* b_h    = (const float*)d_in[3];   // (512,)
    float* out = (float*)d_out;                    // (16384, 1024)

    unsigned short* Abf = (unsigned short*)d_ws;                          // 16 MiB
    unsigned short* Wbf = (unsigned short*)((char*)d_ws + (size_t)16384 * 512 * 2);

    const int nA4 = (16384 * 512) / 4;
    const int nW4 = (1024 * 512) / 4;
    cvt_both<<<2048, 256, 0, stream>>>(inputs, w_ih, Abf, Wbf, nA4, nA4 + nW4);

    // fused GEMM + modReLU: 64 m-blocks x 4 col-blocks = 256 blocks (1/CU)
    gemm_modrelu<<<256, 512, 0, stream>>>(Abf, Wbf, b_h, out);
}